// Round 18
// baseline (130.039 us; speedup 1.0000x reference)
//
#include <hip/hip_runtime.h>

// Problem constants (from reference)
constexpr int B  = 8;
constexpr int T  = 256;
constexpr int U1 = 65;
constexpr int DK = 640;    // D_ENC == D_pred
constexpr int V  = 1024;

constexpr int M_ENC  = B * T;    // 2048
constexpr int M_PRED = B * U1;   // 520

constexpr int NKS  = DK / 32;    // 20 k-steps
constexpr int RT_E = M_ENC / 16; // 128 A row-tiles (enc)
constexpr int RT_P = 36;         // pred row-tiles padded (576 rows >= 520)
constexpr int CT   = V / 16;     // 64 B col-tiles

typedef float  f32x4  __attribute__((ext_vector_type(4)));
typedef short  short8 __attribute__((ext_vector_type(8)));
typedef unsigned short u16x4 __attribute__((ext_vector_type(4)));

__device__ __forceinline__ short f2bf(float f) {
    union { float f; unsigned u; } x; x.f = f;
    unsigned r = x.u + 0x7fffu + ((x.u >> 16) & 1u);
    return (short)(r >> 16);
}
__device__ __forceinline__ f32x4 bf4_to_f32(u16x4 s) {
    f32x4 o;
    union { unsigned u; float f; } x;
    x.u = ((unsigned)s[0]) << 16; o[0] = x.f;
    x.u = ((unsigned)s[1]) << 16; o[1] = x.f;
    x.u = ((unsigned)s[2]) << 16; o[2] = x.f;
    x.u = ((unsigned)s[3]) << 16; o[3] = x.f;
    return o;
}

// ---------------------------------------------------------------------------
// prep: emit MFMA-fragment-major packed operands (frozen from R14).
// ---------------------------------------------------------------------------
constexpr int NB_AE = RT_E * NKS * 64 / 256;  // 640 blocks
constexpr int NB_AP = RT_P * NKS * 64 / 256;  // 180
constexpr int NB_BE = CT   * NKS * 64 / 256;  // 320
constexpr int NB_BP = NB_BE;                  // 320

__global__ __launch_bounds__(256) void prep_kernel(
    const float* __restrict__ enc, const float* __restrict__ pred,
    const float* __restrict__ W,
    short* __restrict__ Apack_e, short* __restrict__ Apack_p,
    short* __restrict__ Bpack_e, short* __restrict__ Bpack_p)
{
    const int bid = blockIdx.x;
    const int tid = threadIdx.x;

    if (bid < NB_AE) {                     // ---- A-pack enc ----
        const int chunk = bid * 256 + tid;
        const int l  = chunk & 63;
        const int ks = (chunk >> 6) % NKS;
        const int rt = chunk / (64 * NKS);
        const int row = rt * 16 + (l & 15);
        const float* src = enc + (size_t)row * DK + ks * 32 + (l >> 4) * 8;
        const f32x4 x = *reinterpret_cast<const f32x4*>(src);
        const f32x4 y = *reinterpret_cast<const f32x4*>(src + 4);
        short8 s;
        s[0]=f2bf(x[0]); s[1]=f2bf(x[1]); s[2]=f2bf(x[2]); s[3]=f2bf(x[3]);
        s[4]=f2bf(y[0]); s[5]=f2bf(y[1]); s[6]=f2bf(y[2]); s[7]=f2bf(y[3]);
        *reinterpret_cast<short8*>(Apack_e + (size_t)chunk * 8) = s;
    } else if (bid < NB_AE + NB_AP) {      // ---- A-pack pred (zero-padded) ----
        const int chunk = (bid - NB_AE) * 256 + tid;
        const int l  = chunk & 63;
        const int ks = (chunk >> 6) % NKS;
        const int rt = chunk / (64 * NKS);
        const int row = rt * 16 + (l & 15);
        short8 s;
        if (row < M_PRED) {
            const float* src = pred + (size_t)row * DK + ks * 32 + (l >> 4) * 8;
            const f32x4 x = *reinterpret_cast<const f32x4*>(src);
            const f32x4 y = *reinterpret_cast<const f32x4*>(src + 4);
            s[0]=f2bf(x[0]); s[1]=f2bf(x[1]); s[2]=f2bf(x[2]); s[3]=f2bf(x[3]);
            s[4]=f2bf(y[0]); s[5]=f2bf(y[1]); s[6]=f2bf(y[2]); s[7]=f2bf(y[3]);
        } else {
            #pragma unroll
            for (int j = 0; j < 8; ++j) s[j] = 0;
        }
        *reinterpret_cast<short8*>(Apack_p + (size_t)chunk * 8) = s;
    } else {                               // ---- B-pack enc / pred ----
        const bool isE = (bid < NB_AE + NB_AP + NB_BE);
        const int  base = isE ? (NB_AE + NB_AP) : (NB_AE + NB_AP + NB_BE);
        short* Bp = isE ? Bpack_e : Bpack_p;
        const int kofs = isE ? 0 : DK;
        const int chunk = (bid - base) * 256 + tid;
        const int l  = chunk & 63;
        const int ks = (chunk >> 6) % NKS;
        const int ct = chunk / (64 * NKS);
        const int v  = ct * 16 + (l & 15);
        const int k0 = kofs + ks * 32 + (l >> 4) * 8;
        short8 s;
        #pragma unroll
        for (int j = 0; j < 8; ++j)
            s[j] = f2bf(W[(size_t)(k0 + j) * V + v]);
        *reinterpret_cast<short8*>(Bp + (size_t)chunk * 8) = s;
    }
}

// ---------------------------------------------------------------------------
// pred GEMM (frozen from R14): 144 blocks, writes pred_proj (bf16, +bias).
// ---------------------------------------------------------------------------
constexpr int NB_GP = (RT_P / 4) * 16;       // 144

__global__ __launch_bounds__(256) void gemm_pred_kernel(
    const short* __restrict__ Apack_p, const short* __restrict__ Bpack_p,
    const float* __restrict__ bias, short* __restrict__ pred_proj)
{
    const int rb = blockIdx.x >> 4;
    const int cb = blockIdx.x & 15;

    const int wid  = threadIdx.x >> 6;
    const int lane = threadIdx.x & 63;
    const int wr   = wid >> 1, wc = wid & 1;
    const int m    = lane & 15, g = lane >> 4;

    const int rt0 = rb * 4 + wr * 2;
    const int ct0 = cb * 4 + wc * 2;

    const short* a0p = Apack_p + ((size_t)rt0 * NKS) * 512 + lane * 8;
    const short* a1p = a0p + (size_t)NKS * 512;
    const short* b0p = Bpack_p + ((size_t)ct0 * NKS) * 512 + lane * 8;
    const short* b1p = b0p + (size_t)NKS * 512;

    f32x4 z4; z4[0]=z4[1]=z4[2]=z4[3]=0.f;
    f32x4 acc00 = z4, acc01 = z4, acc10 = z4, acc11 = z4;

    #pragma unroll 4
    for (int ks = 0; ks < NKS; ++ks) {
        const size_t o = (size_t)ks * 512;
        const short8 a0 = *reinterpret_cast<const short8*>(a0p + o);
        const short8 a1 = *reinterpret_cast<const short8*>(a1p + o);
        const short8 b0 = *reinterpret_cast<const short8*>(b0p + o);
        const short8 b1 = *reinterpret_cast<const short8*>(b1p + o);
        acc00 = __builtin_amdgcn_mfma_f32_16x16x32_bf16(a0, b0, acc00, 0, 0, 0);
        acc01 = __builtin_amdgcn_mfma_f32_16x16x32_bf16(a0, b1, acc01, 0, 0, 0);
        acc10 = __builtin_amdgcn_mfma_f32_16x16x32_bf16(a1, b0, acc10, 0, 0, 0);
        acc11 = __builtin_amdgcn_mfma_f32_16x16x32_bf16(a1, b1, acc11, 0, 0, 0);
    }

    #pragma unroll
    for (int nt = 0; nt < 2; ++nt) {
        const int col = (ct0 + nt) * 16 + m;
        const float bv = bias[col];
        #pragma unroll
        for (int mt = 0; mt < 2; ++mt) {
            const f32x4 a = nt ? (mt ? acc11 : acc01) : (mt ? acc10 : acc00);
            #pragma unroll
            for (int q = 0; q < 4; ++q) {
                const int row = (rt0 + mt) * 16 + g * 4 + q;
                if (row < M_PRED)
                    pred_proj[(size_t)row * V + col] = f2bf(a[q] + bv);
            }
        }
    }
}

// ---------------------------------------------------------------------------
// FUSED enc-GEMM + broadcast-write (R18).
// Grid: 128 row-tiles x 8 col-parts = 1024 blocks (bcast-proven count).
// Phase 0: stage pred_proj[b][:, col0:+128] -> LDS (bf16, 16.6 KB, L2-hits)
// Phase 1: MFMA 16x128 tile; wave w owns cols [32w,32w+32) (2 acc tiles)
// Phase 2: acc -> LDS bf16 (numerics identical to old enc_proj roundtrip)
// Phase 3: R16-bcast-style write loop: e in regs, p from LDS, f32x4 stores
// ---------------------------------------------------------------------------
__global__ __launch_bounds__(256) void fused_kernel(
    const short* __restrict__ Apack_e, const short* __restrict__ Bpack_e,
    const short* __restrict__ pred_proj, float* __restrict__ out)
{
    __shared__ short p_s[U1 * 128];      // 65 x 128 bf16 = 16640 shorts
    __shared__ short e_s[16 * 128];      // 16 x 128 bf16

    const int rt   = blockIdx.x >> 3;    // 0..127 (16-row tile)
    const int cp   = blockIdx.x & 7;     // 0..7   (128-col part)
    const int b    = rt >> 4;            // 16 row-tiles per batch
    const int col0 = cp * 128;
    const int tid  = threadIdx.x;

    // ---- phase 0: p -> LDS ----
    for (int i = tid; i < U1 * 16; i += 256) {
        const int u = i >> 4;
        const int c = (i & 15) * 8;
        *reinterpret_cast<short8*>(p_s + u * 128 + c) =
            *reinterpret_cast<const short8*>(
                pred_proj + ((size_t)(b * U1 + u)) * V + col0 + c);
    }

    // ---- phase 1: GEMM ----
    const int wid  = tid >> 6;
    const int lane = tid & 63;
    const int m    = lane & 15, g = lane >> 4;

    const short* ap  = Apack_e + ((size_t)rt * NKS) * 512 + lane * 8;
    const int   ct0  = cp * 8 + wid * 2;          // 16-col tile index
    const short* b0p = Bpack_e + ((size_t)ct0 * NKS) * 512 + lane * 8;
    const short* b1p = b0p + (size_t)NKS * 512;

    f32x4 z4; z4[0]=z4[1]=z4[2]=z4[3]=0.f;
    f32x4 acc0 = z4, acc1 = z4;

    #pragma unroll 4
    for (int ks = 0; ks < NKS; ++ks) {
        const size_t o = (size_t)ks * 512;
        const short8 a  = *reinterpret_cast<const short8*>(ap  + o);
        const short8 b0 = *reinterpret_cast<const short8*>(b0p + o);
        const short8 b1 = *reinterpret_cast<const short8*>(b1p + o);
        acc0 = __builtin_amdgcn_mfma_f32_16x16x32_bf16(a, b0, acc0, 0, 0, 0);
        acc1 = __builtin_amdgcn_mfma_f32_16x16x32_bf16(a, b1, acc1, 0, 0, 0);
    }

    // ---- phase 2: acc -> LDS bf16 ----
    #pragma unroll
    for (int nt = 0; nt < 2; ++nt) {
        const f32x4 a = nt ? acc1 : acc0;
        const int col = wid * 32 + nt * 16 + m;
        #pragma unroll
        for (int q = 0; q < 4; ++q)
            e_s[(g * 4 + q) * 128 + col] = f2bf(a[q]);
    }
    __syncthreads();

    // ---- phase 3: broadcast write (R16 bcast structure) ----
    const int c4 = tid & 31;            // f32x4 col chunk (0..31)
    const int r8 = tid >> 5;            // 0..7
    const f32x4 e0 = bf4_to_f32(*reinterpret_cast<const u16x4*>(
        e_s + r8 * 128 + c4 * 4));
    const f32x4 e1 = bf4_to_f32(*reinterpret_cast<const u16x4*>(
        e_s + (8 + r8) * 128 + c4 * 4));

    float* o0 = out + ((size_t)(rt * 16 + r8) * U1) * V + col0 + c4 * 4;
    float* o1 = out + ((size_t)(rt * 16 + 8 + r8) * U1) * V + col0 + c4 * 4;

    for (int u = 0; u < U1; ++u) {
        const f32x4 pf = bf4_to_f32(*reinterpret_cast<const u16x4*>(
            p_s + u * 128 + c4 * 4));
        *reinterpret_cast<f32x4*>(o0 + (size_t)u * V) = e0 + pf;
        *reinterpret_cast<f32x4*>(o1 + (size_t)u * V) = e1 + pf;
    }
}

extern "C" void kernel_launch(void* const* d_in, const int* in_sizes, int n_in,
                              void* d_out, int out_size, void* d_ws, size_t ws_size,
                              hipStream_t stream)
{
    const float* enc  = (const float*)d_in[0];   // (8,256,640)
    const float* pred = (const float*)d_in[1];   // (8,65,640)
    const float* W    = (const float*)d_in[2];   // (1280,1024)
    const float* bias = (const float*)d_in[3];   // (1024,)
    float* out = (float*)d_out;                  // (8,256,65,1024)

    // ws layout in shorts (6.5 MB; ws ≈ 2.18 GB per fill-dispatch evidence).
    short* Apack_e  = (short*)d_ws;                                   // 1,310,720
    short* Apack_p  = Apack_e + (size_t)RT_E * NKS * 512;             //   368,640
    short* Bpack_e  = Apack_p + (size_t)RT_P * NKS * 512;             //   655,360
    short* Bpack_p  = Bpack_e + (size_t)CT * NKS * 512;               //   655,360
    short* pred_proj = Bpack_p + (size_t)CT * NKS * 512;              //   532,480

    prep_kernel<<<NB_AE + NB_AP + NB_BE + NB_BP, 256, 0, stream>>>(
        enc, pred, W, Apack_e, Apack_p, Bpack_e, Bpack_p);

    gemm_pred_kernel<<<NB_GP, 256, 0, stream>>>(
        Apack_p, Bpack_p, bias, pred_proj);

    fused_kernel<<<RT_E * 8, 256, 0, stream>>>(
        Apack_e, Bpack_e, pred_proj, out);
}